// Round 1
// 684.343 us; speedup vs baseline: 1.0653x; 1.0653x over previous
//
#include <hip/hip_runtime.h>
#include <math.h>

// HMLSTMOutput — fp32 in/out buffers; internal bf16 MFMA.
// R7: replace the 128²/2-barrier m97-style GEMM (582 TF, MfmaUtil 24%) with the 256²
// 8-phase schedule (T3+T4 counted vmcnt(6) + T2 swizzle + T5 setprio + T1 XCD swizzle):
// BM=BN=256, BK=64, 8 waves (2Mx4N), 128KB LDS 2-tile double buffer. 4 phases per K-tile,
// one half-tile (2x global_load_lds) staged per phase into provably-dead LDS regions:
//   q0: A.rows[64,128) of tile t+1 (other buffer)
//   q1: B-h0 of tile t+2 (B regs captured in phase 0 -> region dead)
//   q2: B-h1 of tile t+2
//   q3: A.rows[0,64) of tile t+2 (last read in phase 1)
// => exactly 6 loads (3 half-tiles) in flight at each tile boundary -> s_waitcnt vmcnt(6).

typedef __attribute__((ext_vector_type(8))) short short8;   // 8 bf16 = 4 VGPRs (MFMA A/B frag)
typedef __attribute__((ext_vector_type(4))) float float4v;  // MFMA C/D frag

#define DEV __device__ __forceinline__

DEV unsigned short f2bf(float f){
    union{float f; unsigned int i;} c; c.f = f;
    unsigned int r = c.i + 0x7fffu + ((c.i>>16)&1u);   // round-to-nearest-even
    return (unsigned short)(r>>16);
}
DEV unsigned int pack2(float a, float b){
    return (unsigned int)f2bf(a) | ((unsigned int)f2bf(b)<<16);
}

// direct global->LDS DMA, 16 B per lane; LDS dest = wave-uniform base + lane*16
DEV void gload_lds16(const unsigned short* g, unsigned short* l){
    __builtin_amdgcn_global_load_lds((const __attribute__((address_space(1))) void*)g,
                                     (__attribute__((address_space(3))) void*)l, 16, 0, 0);
}

// -------- convert fp32 -> bf16, flat (W1, W2, Wo). 8 elems / thread ----------
__global__ __launch_bounds__(256) void cvt_flat(const float* __restrict__ src,
                                                unsigned short* __restrict__ dst, int n8)
{
    int v = blockIdx.x*256 + threadIdx.x;
    if(v >= n8) return;
    const float4* s = (const float4*)(src) + v*2;
    float4 a = s[0], b = s[1];
    uint4 o;
    o.x = pack2(a.x, a.y); o.y = pack2(a.z, a.w);
    o.z = pack2(b.x, b.y); o.w = pack2(b.z, b.w);
    *((uint4*)dst + v) = o;
}

// -------- We [3,1024,512] fp32 -> Wep [1024,1536] bf16 (repack + convert) -------
__global__ __launch_bounds__(256) void cvt_we(const float* __restrict__ We,
                                              unsigned short* __restrict__ Wep)
{
    int v  = blockIdx.x*256 + threadIdx.x;   // 196608 vectors of 8 elems
    int i8 = v & 63;
    int e  = (v>>6) & 1023;
    int l  = v>>16;
    const float4* s = (const float4*)(We + (size_t)l*524288 + (size_t)e*512 + i8*8);
    float4 a = s[0], b = s[1];
    uint4 o;
    o.x = pack2(a.x, a.y); o.y = pack2(a.z, a.w);
    o.z = pack2(b.x, b.y); o.w = pack2(b.z, b.w);
    *(uint4*)(Wep + (size_t)e*1536 + (size_t)l*512 + i8*8) = o;
}

// -------- gates: g[l] = sigmoid(x_row . Wg[l]) fp32; u = bf16(x * g[chunk]) -----
__global__ __launch_bounds__(256) void gate_u(const float* __restrict__ x,
                                              const float* __restrict__ Wg,
                                              unsigned short* __restrict__ u)
{
    int row  = blockIdx.x*4 + (threadIdx.x>>6);
    int lane = threadIdx.x & 63;
    const float4* xr = (const float4*)(x + (size_t)row*1536);
    float4 hv[6];
    #pragma unroll
    for(int j=0;j<6;j++) hv[j] = xr[j*64 + lane];

    float p[3];
    #pragma unroll
    for(int l=0;l<3;l++){
        const float4* wr = (const float4*)(Wg + (size_t)l*1536);
        float s = 0.f;
        #pragma unroll
        for(int j=0;j<6;j++){
            float4 wv = wr[j*64 + lane];
            s += hv[j].x*wv.x + hv[j].y*wv.y + hv[j].z*wv.z + hv[j].w*wv.w;
        }
        p[l] = s;
    }
    #pragma unroll
    for(int off=32; off; off>>=1){
        p[0] += __shfl_xor(p[0], off);
        p[1] += __shfl_xor(p[1], off);
        p[2] += __shfl_xor(p[2], off);
    }
    float g[3];
    #pragma unroll
    for(int l=0;l<3;l++) g[l] = 1.f/(1.f + __expf(-p[l]));

    uint2* ur = (uint2*)(u + (size_t)row*1536);
    #pragma unroll
    for(int j=0;j<6;j++){
        float gj = g[(j*64+lane)>>7];   // float4 f=j*64+lane covers [4f,4f+4) -> chunk f>>7
        uint2 o;
        o.x = pack2(hv[j].x*gj, hv[j].y*gj);
        o.y = pack2(hv[j].z*gj, hv[j].w*gj);
        ur[j*64 + lane] = o;
    }
}

// ---- GEMM: C[M,N] = act(A[M,K] @ W[N,K]^T + bias)  (bf16 in, fp32 acc) ----
// 256x256 tile, BK=64, 8 waves (2Mx4N), per-wave 128x64 output (acc[8][4] frags).
// 8-phase (4 per K-tile) schedule: per phase {ds_read subtile, stage 1 half-tile,
// barrier, setprio(1), 16 MFMA, setprio(0), barrier}; counted vmcnt(6) at boundary.
template<int ACT, int BIAS_ROWS, bool F32OUT>
__global__ __launch_bounds__(512, 2) void gemm256(
    const unsigned short* __restrict__ A,
    const unsigned short* __restrict__ W,
    const float* __restrict__ bias,
    void* __restrict__ Cv,
    int M, int N, int K)
{
    // [buf(2)][half(2)][128 rows][64 cols] each; 64 KB + 64 KB = 128 KB
    __shared__ __align__(128) unsigned short As[2*2*128*64];
    __shared__ __align__(128) unsigned short Bs[2*2*128*64];

    const int tid = threadIdx.x;
    const int nb  = N >> 8;            // n-tiles
    const int mt  = M >> 8;            // m-tiles (divisible by 8)
    const int xcd = blockIdx.x & 7;    // XCD-exclusive bm range (bijective: grid%8==0)
    const int j   = blockIdx.x >> 3;
    const int bm  = xcd*(mt>>3) + j/nb;
    const int bn  = j % nb;
    const int m0  = bm << 8, n0 = bn << 8;

    const int lane = tid & 63, wid = tid >> 6;
    const int wm = wid >> 2, wn = wid & 3;          // 2x4 wave grid
    const int lr = lane & 15, quad = lane >> 4, sx = lr & 7;
    const int srow = lane >> 3;                     // staging: row within 8-row slice
    const int scb  = (lane & 7) ^ srow;             // pre-swizzled source col-block
    const size_t aoff = (size_t)srow*K + scb*8;
    const int nt = K >> 6;

    float4v acc[8][4];
    #pragma unroll
    for(int i=0;i<8;i++)
        #pragma unroll
        for(int jj=0;jj<4;jj++) acc[i][jj] = (float4v){0.f,0.f,0.f,0.f};

    // stage one 64-row group: half h (0/1), load l (rows l*64..l*64+64), K-tile s.
    // LDS dest linear (wave-uniform base + lane*16); swizzle realized via source addr:
    // stored slot sb at row r holds logical col-block sb^(r&7).
#define STAGE_A(h,l,s) gload_lds16(A + ((size_t)(m0 + (h)*128 + (l)*64 + wid*8))*K + (s)*64 + aoff, \
                                   &As[(((s)&1)*2+(h))*8192 + ((l)*64 + wid*8)*64])
#define STAGE_B(h,l,s) gload_lds16(W + ((size_t)(n0 + (h)*128 + (l)*64 + wid*8))*K + (s)*64 + aoff, \
                                   &Bs[(((s)&1)*2+(h))*8192 + ((l)*64 + wid*8)*64])

    // ---- prologue: tile0 fully (8 loads) + tile1's B halves and A.rows[0,64) (6) ----
    STAGE_A(0,0,0); STAGE_A(0,1,0); STAGE_A(1,0,0); STAGE_A(1,1,0);
    STAGE_B(0,0,0); STAGE_B(0,1,0); STAGE_B(1,0,0); STAGE_B(1,1,0);
    if(nt > 1){
        STAGE_B(0,0,1); STAGE_B(0,1,1); STAGE_B(1,0,1); STAGE_B(1,1,1);
        STAGE_A(0,0,1); STAGE_A(1,0,1);
        asm volatile("s_waitcnt vmcnt(6)" ::: "memory");   // tile0 landed; tile1 3ht in flight
    } else {
        asm volatile("s_waitcnt vmcnt(0)" ::: "memory");
    }
    __builtin_amdgcn_s_barrier();

    for(int t=0; t<nt; ++t){
        const int cur = t & 1;
        const unsigned short* Ab = &As[(cur*2 + wm)*8192];                    // wave's A half
        const unsigned short* Bb = &Bs[(cur*2 + (wn>>1))*8192 + (wn&1)*4096]; // wave's 64 B rows
        short8 bfr[4][2];
        #pragma unroll
        for(int q=0; q<4; ++q){
            // ---- ds-load register subtile: A mi-quarter (4 reads); +B all (8) at q0 ----
            short8 af[2][2];
            #pragma unroll
            for(int mi=0; mi<2; ++mi)
                #pragma unroll
                for(int ks=0; ks<2; ++ks)
                    af[mi][ks] = *(const short8*)&Ab[(q*32 + mi*16 + lr)*64 + (((ks*4+quad)^sx)*8)];
            if(q==0){
                #pragma unroll
                for(int ni=0; ni<4; ++ni)
                    #pragma unroll
                    for(int ks=0; ks<2; ++ks)
                        bfr[ni][ks] = *(const short8*)&Bb[(ni*16 + lr)*64 + (((ks*4+quad)^sx)*8)];
            }
            // ---- stage 1 half-tile into a dead region ----
            if(q==0)      { if(t+1 < nt){ STAGE_A(0,1,t+1); STAGE_A(1,1,t+1); } } // other buffer
            else if(q==1) { if(t+2 < nt){ STAGE_B(0,0,t+2); STAGE_B(0,1,t+2); } } // B dead after q0
            else if(q==2) { if(t+2 < nt){ STAGE_B(1,0,t+2); STAGE_B(1,1,t+2); } }
            else          { if(t+2 < nt){ STAGE_A(0,0,t+2); STAGE_A(1,0,t+2); } } // rows[0,64) dead after q1
            __builtin_amdgcn_s_barrier();
            __builtin_amdgcn_s_setprio(1);
            #pragma unroll
            for(int ks=0; ks<2; ++ks)
                #pragma unroll
                for(int mi=0; mi<2; ++mi)
                    #pragma unroll
                    for(int ni=0; ni<4; ++ni)
                        acc[q*2+mi][ni] = __builtin_amdgcn_mfma_f32_16x16x32_bf16(
                            af[mi][ks], bfr[ni][ks], acc[q*2+mi][ni], 0, 0, 0);
            __builtin_amdgcn_s_setprio(0);
            if(q < 3) __builtin_amdgcn_s_barrier();
        }
        // ---- tile boundary: next tile fully landed; 6 loads (3 half-tiles) stay in flight ----
        if(t+2 < nt) asm volatile("s_waitcnt vmcnt(6)" ::: "memory");
        else         asm volatile("s_waitcnt vmcnt(0)" ::: "memory");
        __builtin_amdgcn_s_barrier();
    }
#undef STAGE_A
#undef STAGE_B

    // epilogue: C/D layout col(n)=lane&15, row(m)=quad*4+reg (m89/m91-verified)
    #pragma unroll
    for(int ni=0; ni<4; ++ni){
        const int n = n0 + wn*64 + ni*16 + lr;
        float bsum = 0.f;
        #pragma unroll
        for(int r=0; r<BIAS_ROWS; ++r) bsum += bias[(size_t)r*N + n];
        #pragma unroll
        for(int Q=0; Q<8; ++Q){
            #pragma unroll
            for(int reg=0; reg<4; ++reg){
                const int m = m0 + wm*128 + Q*16 + quad*4 + reg;
                float v = acc[Q][ni][reg] + bsum;
                if(ACT==1)      v = fmaxf(v, 0.f);
                else if(ACT==2) v = tanhf(v);
                if constexpr (F32OUT) ((float*)Cv)[(size_t)m*N + n] = v;
                else                  ((unsigned short*)Cv)[(size_t)m*N + n] = f2bf(v);
            }
        }
    }
}

extern "C" void kernel_launch(void* const* d_in, const int* in_sizes, int n_in,
                              void* d_out, int out_size, void* d_ws, size_t ws_size,
                              hipStream_t stream)
{
    const float* x  = (const float*)d_in[0];
    const float* Wg = (const float*)d_in[1];
    const float* We = (const float*)d_in[2];
    const float* be = (const float*)d_in[3];
    const float* W1 = (const float*)d_in[4];
    const float* b1 = (const float*)d_in[5];
    const float* W2 = (const float*)d_in[6];
    const float* b2 = (const float*)d_in[7];
    const float* Wo = (const float*)d_in[8];
    const float* bo = (const float*)d_in[9];
    float* out = (float*)d_out;

    const int M = 32768;    // B*T

    // workspace: 8 MB weights + 96 MB slotA + 64 MB slotB = 168 MB
    char* w = (char*)d_ws;
    unsigned short* Wep   = (unsigned short*)w; w += (size_t)1024*1536*2;  //  3 MB
    unsigned short* W1b   = (unsigned short*)w; w += (size_t)1024*1024*2;  //  2 MB
    unsigned short* W2b   = (unsigned short*)w; w += (size_t)1024*1024*2;  //  2 MB
    unsigned short* Wob   = (unsigned short*)w; w += (size_t)512*1024*2;   //  1 MB
    unsigned short* slotA = (unsigned short*)w; w += (size_t)M*1536*2;     // 96 MB
    unsigned short* slotB = (unsigned short*)w; w += (size_t)M*1024*2;     // 64 MB
    unsigned short* u  = slotA;   // [M,1536]
    unsigned short* o1 = slotA;   // [M,1024] (u dead after GEMM-1)
    unsigned short* he = slotB;   // [M,1024]
    unsigned short* o2 = slotB;   // [M,1024] (he dead after GEMM-2)

    hipLaunchKernelGGL(cvt_flat, dim3(512), dim3(256), 0, stream, W1, W1b, 131072);
    hipLaunchKernelGGL(cvt_flat, dim3(512), dim3(256), 0, stream, W2, W2b, 131072);
    hipLaunchKernelGGL(cvt_flat, dim3(256), dim3(256), 0, stream, Wo, Wob, 65536);
    hipLaunchKernelGGL(cvt_we,   dim3(768), dim3(256), 0, stream, We, Wep);

    hipLaunchKernelGGL(gate_u, dim3(M/4), dim3(256), 0, stream, x, Wg, u);
    hipLaunchKernelGGL((gemm256<1,3,false>), dim3((M/256)*(1024/256)), dim3(512), 0, stream,
                       u,  Wep, be, he,  M, 1024, 1536);
    hipLaunchKernelGGL((gemm256<2,1,false>), dim3((M/256)*(1024/256)), dim3(512), 0, stream,
                       he, W1b, b1, o1,  M, 1024, 1024);
    hipLaunchKernelGGL((gemm256<2,1,false>), dim3((M/256)*(1024/256)), dim3(512), 0, stream,
                       o1, W2b, b2, o2,  M, 1024, 1024);
    hipLaunchKernelGGL((gemm256<0,1,true>),  dim3((M/256)*(512/256)),  dim3(512), 0, stream,
                       o2, Wob, bo, out, M, 512, 1024);
}

// Round 2
// 652.417 us; speedup vs baseline: 1.1174x; 1.0489x over previous
//
#include <hip/hip_runtime.h>
#include <math.h>

// HMLSTMOutput — fp32 in/out buffers; internal bf16 MFMA.
// R8: (a) exact m201-template conformance for the 256² 8-phase GEMM: K-loop unrolled x2
//     (static LDS buffer parity), explicit s_waitcnt lgkmcnt(8) pre-barrier on the 12-read
//     phase and lgkmcnt(0) post-barrier (template lines); (b) fused prep kernel (gate_u +
//     all weight converts) replaces 5 launches with 1.
// R7 result: 8-phase +26% (582->735 TF GEMM-1, MfmaUtil 24->30.5%) but ~3000 cyc/tile of
// unexplained stall vs m201's 3300 cyc/tile total; testing whether runtime-indexed dbuf +
// compiler-placed lgkm waits are the difference.

typedef __attribute__((ext_vector_type(8))) short short8;   // 8 bf16 = 4 VGPRs (MFMA A/B frag)
typedef __attribute__((ext_vector_type(4))) float float4v;  // MFMA C/D frag

#define DEV __device__ __forceinline__

DEV unsigned short f2bf(float f){
    union{float f; unsigned int i;} c; c.f = f;
    unsigned int r = c.i + 0x7fffu + ((c.i>>16)&1u);   // round-to-nearest-even
    return (unsigned short)(r>>16);
}
DEV unsigned int pack2(float a, float b){
    return (unsigned int)f2bf(a) | ((unsigned int)f2bf(b)<<16);
}

// direct global->LDS DMA, 16 B per lane; LDS dest = wave-uniform base + lane*16
DEV void gload_lds16(const unsigned short* g, unsigned short* l){
    __builtin_amdgcn_global_load_lds((const __attribute__((address_space(1))) void*)g,
                                     (__attribute__((address_space(3))) void*)l, 16, 0, 0);
}

// ---------------- fused prep: gates+u and all weight converts (1 launch) ----------------
// blocks [0,8192): gate_u (4 rows each)
// blocks [8192,9472): flat fp32->bf16 (W1 512 blk, W2 512, Wo 256)
// blocks [9472,10240): We [3,1024,512] -> Wep [1024,1536] repack+convert
__global__ __launch_bounds__(256) void prep(
    const float* __restrict__ x,  const float* __restrict__ Wg,
    const float* __restrict__ W1, const float* __restrict__ W2,
    const float* __restrict__ Wo, const float* __restrict__ We,
    unsigned short* __restrict__ u,   unsigned short* __restrict__ W1b,
    unsigned short* __restrict__ W2b, unsigned short* __restrict__ Wob,
    unsigned short* __restrict__ Wep)
{
    int b = blockIdx.x;
    if(b < 8192){
        int row  = b*4 + (threadIdx.x>>6);
        int lane = threadIdx.x & 63;
        const float4* xr = (const float4*)(x + (size_t)row*1536);
        float4 hv[6];
        #pragma unroll
        for(int j=0;j<6;j++) hv[j] = xr[j*64 + lane];

        float p[3];
        #pragma unroll
        for(int l=0;l<3;l++){
            const float4* wr = (const float4*)(Wg + (size_t)l*1536);
            float s = 0.f;
            #pragma unroll
            for(int j=0;j<6;j++){
                float4 wv = wr[j*64 + lane];
                s += hv[j].x*wv.x + hv[j].y*wv.y + hv[j].z*wv.z + hv[j].w*wv.w;
            }
            p[l] = s;
        }
        #pragma unroll
        for(int off=32; off; off>>=1){
            p[0] += __shfl_xor(p[0], off);
            p[1] += __shfl_xor(p[1], off);
            p[2] += __shfl_xor(p[2], off);
        }
        float g[3];
        #pragma unroll
        for(int l=0;l<3;l++) g[l] = 1.f/(1.f + __expf(-p[l]));

        uint2* ur = (uint2*)(u + (size_t)row*1536);
        #pragma unroll
        for(int j=0;j<6;j++){
            float gj = g[(j*64+lane)>>7];   // float4 f=j*64+lane covers [4f,4f+4) -> chunk f>>7
            uint2 o;
            o.x = pack2(hv[j].x*gj, hv[j].y*gj);
            o.y = pack2(hv[j].z*gj, hv[j].w*gj);
            ur[j*64 + lane] = o;
        }
        return;
    }
    b -= 8192;
    if(b < 1280){
        const float* src; unsigned short* dst; int v0;
        if(b < 512)      { src = W1; dst = W1b; v0 = b<<8; }
        else if(b < 1024){ src = W2; dst = W2b; v0 = (b-512)<<8; }
        else             { src = Wo; dst = Wob; v0 = (b-1024)<<8; }
        int v = v0 + threadIdx.x;
        const float4* s = (const float4*)(src) + (size_t)v*2;
        float4 a = s[0], c = s[1];
        uint4 o;
        o.x = pack2(a.x, a.y); o.y = pack2(a.z, a.w);
        o.z = pack2(c.x, c.y); o.w = pack2(c.z, c.w);
        *((uint4*)dst + v) = o;
        return;
    }
    b -= 1280;
    int v  = b*256 + threadIdx.x;   // 196608 vectors of 8 elems
    int i8 = v & 63;
    int e  = (v>>6) & 1023;
    int l  = v>>16;
    const float4* s = (const float4*)(We + (size_t)l*524288 + (size_t)e*512 + i8*8);
    float4 a = s[0], c = s[1];
    uint4 o;
    o.x = pack2(a.x, a.y); o.y = pack2(a.z, a.w);
    o.z = pack2(c.x, c.y); o.w = pack2(c.z, c.w);
    *(uint4*)(Wep + (size_t)e*1536 + (size_t)l*512 + i8*8) = o;
}

// ---- GEMM: C[M,N] = act(A[M,K] @ W[N,K]^T + bias)  (bf16 in, fp32 acc) ----
// 256x256 tile, BK=64, 8 waves (2Mx4N), per-wave 128x64 output (acc[8][4] frags).
// m201 template: K-loop x2-unrolled (static buffer parity), 4 phases/K-tile, per phase
// {ds_read subtile, stage 1 half-tile, [lgkmcnt(8) if 12 reads], barrier, lgkmcnt(0),
//  setprio(1), 16 MFMA, setprio(0), barrier}; counted vmcnt(6) once per K-tile.
template<int ACT, int BIAS_ROWS, bool F32OUT>
__global__ __launch_bounds__(512, 2) void gemm256(
    const unsigned short* __restrict__ A,
    const unsigned short* __restrict__ W,
    const float* __restrict__ bias,
    void* __restrict__ Cv,
    int M, int N, int K)
{
    // [buf(2)][half(2)][128 rows][64 cols] each; 64 KB + 64 KB = 128 KB
    __shared__ __align__(128) unsigned short As[2*2*128*64];
    __shared__ __align__(128) unsigned short Bs[2*2*128*64];

    const int tid = threadIdx.x;
    const int nb  = N >> 8;            // n-tiles
    const int mt  = M >> 8;            // m-tiles (divisible by 8)
    const int xcd = blockIdx.x & 7;    // XCD-exclusive bm range (bijective: grid%8==0)
    const int j   = blockIdx.x >> 3;
    const int bm  = xcd*(mt>>3) + j/nb;
    const int bn  = j % nb;
    const int m0  = bm << 8, n0 = bn << 8;

    const int lane = tid & 63, wid = tid >> 6;
    const int wm = wid >> 2, wn = wid & 3;          // 2x4 wave grid
    const int lr = lane & 15, quad = lane >> 4, sx = lr & 7;
    const int srow = lane >> 3;                     // staging: row within 8-row slice
    const int scb  = (lane & 7) ^ srow;             // pre-swizzled source col-block
    const size_t aoff = (size_t)srow*K + scb*8;
    const int nt = K >> 6;             // always even here (24/16)

    float4v acc[8][4];
    #pragma unroll
    for(int i=0;i<8;i++)
        #pragma unroll
        for(int jj=0;jj<4;jj++) acc[i][jj] = (float4v){0.f,0.f,0.f,0.f};

    // stage one 64-row group: half h (0/1), load l (rows l*64..+64), K-tile s, buf parity P.
    // LDS dest linear; swizzle via source addr: stored slot sb at row r = logical cb sb^(r&7).
#define STAGE_A(h,l,s,P) gload_lds16(A + ((size_t)(m0 + (h)*128 + (l)*64 + wid*8))*K + (size_t)(s)*64 + aoff, \
                                     &As[((P)*2+(h))*8192 + ((l)*64 + wid*8)*64])
#define STAGE_B(h,l,s,P) gload_lds16(W + ((size_t)(n0 + (h)*128 + (l)*64 + wid*8))*K + (size_t)(s)*64 + aoff, \
                                     &Bs[((P)*2+(h))*8192 + ((l)*64 + wid*8)*64])

    // ---- prologue: tile0 fully (8 loads) + tile1's B halves and A.rows[0,64) (6) ----
    STAGE_A(0,0,0,0); STAGE_A(0,1,0,0); STAGE_A(1,0,0,0); STAGE_A(1,1,0,0);
    STAGE_B(0,0,0,0); STAGE_B(0,1,0,0); STAGE_B(1,0,0,0); STAGE_B(1,1,0,0);
    STAGE_B(0,0,1,1); STAGE_B(0,1,1,1); STAGE_B(1,0,1,1); STAGE_B(1,1,1,1);
    STAGE_A(0,0,1,1); STAGE_A(1,0,1,1);
    asm volatile("s_waitcnt vmcnt(6)" ::: "memory");   // tile0 landed; tile1 3 half-tiles in flight
    __builtin_amdgcn_s_barrier();

    for(int tt=0; tt<nt; tt+=2){
        #pragma unroll
        for(int uu=0; uu<2; ++uu){
            const int T = tt + uu;                    // runtime tile index; uu = buf parity (static)
            const unsigned short* Ab = &As[(uu*2 + wm)*8192];                    // wave's A half
            const unsigned short* Bb = &Bs[(uu*2 + (wn>>1))*8192 + (wn&1)*4096]; // wave's 64 B rows
            short8 bfr[4][2];
            #pragma unroll
            for(int q=0; q<4; ++q){
                // ---- ds-load register subtile: A mi-quarter (4 reads); +B all (8) at q0 ----
                short8 af[2][2];
                #pragma unroll
                for(int mi=0; mi<2; ++mi)
                    #pragma unroll
                    for(int ks=0; ks<2; ++ks)
                        af[mi][ks] = *(const short8*)&Ab[(q*32 + mi*16 + lr)*64 + (((ks*4+quad)^sx)*8)];
                if(q==0){
                    #pragma unroll
                    for(int ni=0; ni<4; ++ni)
                        #pragma unroll
                        for(int ks=0; ks<2; ++ks)
                            bfr[ni][ks] = *(const short8*)&Bb[(ni*16 + lr)*64 + (((ks*4+quad)^sx)*8)];
                }
                // ---- stage 1 half-tile into a dead region ----
                if(q==0)      { if(T+1 < nt){ STAGE_A(0,1,T+1,1-uu); STAGE_A(1,1,T+1,1-uu); } } // other buffer
                else if(q==1) { if(T+2 < nt){ STAGE_B(0,0,T+2,uu);   STAGE_B(0,1,T+2,uu);   } } // B dead after q0
                else if(q==2) { if(T+2 < nt){ STAGE_B(1,0,T+2,uu);   STAGE_B(1,1,T+2,uu);   } }
                else          { if(T+2 < nt){ STAGE_A(0,0,T+2,uu);   STAGE_A(1,0,T+2,uu);   } } // rows[0,64) dead after q1
                if(q==0) asm volatile("s_waitcnt lgkmcnt(8)");   // 12 reads issued: pre-drain oldest 4
                __builtin_amdgcn_s_barrier();
                asm volatile("s_waitcnt lgkmcnt(0)");
                __builtin_amdgcn_s_setprio(1);
                #pragma unroll
                for(int ks=0; ks<2; ++ks)
                    #pragma unroll
                    for(int mi=0; mi<2; ++mi)
                        #pragma unroll
                        for(int ni=0; ni<4; ++ni)
                            acc[q*2+mi][ni] = __builtin_amdgcn_mfma_f32_16x16x32_bf16(
                                af[mi][ks], bfr[ni][ks], acc[q*2+mi][ni], 0, 0, 0);
                __builtin_amdgcn_s_setprio(0);
                if(q < 3) __builtin_amdgcn_s_barrier();
            }
            // ---- tile boundary: tile T+1 fully landed; 6 loads (3 half-tiles) stay in flight ----
            if(T+2 < nt) asm volatile("s_waitcnt vmcnt(6)" ::: "memory");
            else         asm volatile("s_waitcnt vmcnt(0)" ::: "memory");
            __builtin_amdgcn_s_barrier();
        }
    }
#undef STAGE_A
#undef STAGE_B

    // epilogue: C/D layout col(n)=lane&15, row(m)=quad*4+reg (m89/m91-verified)
    #pragma unroll
    for(int ni=0; ni<4; ++ni){
        const int n = n0 + wn*64 + ni*16 + lr;
        float bsum = 0.f;
        #pragma unroll
        for(int r=0; r<BIAS_ROWS; ++r) bsum += bias[(size_t)r*N + n];
        #pragma unroll
        for(int Q=0; Q<8; ++Q){
            #pragma unroll
            for(int reg=0; reg<4; ++reg){
                const int m = m0 + wm*128 + Q*16 + quad*4 + reg;
                float v = acc[Q][ni][reg] + bsum;
                if(ACT==1)      v = fmaxf(v, 0.f);
                else if(ACT==2) v = tanhf(v);
                if constexpr (F32OUT) ((float*)Cv)[(size_t)m*N + n] = v;
                else                  ((unsigned short*)Cv)[(size_t)m*N + n] = f2bf(v);
            }
        }
    }
}

extern "C" void kernel_launch(void* const* d_in, const int* in_sizes, int n_in,
                              void* d_out, int out_size, void* d_ws, size_t ws_size,
                              hipStream_t stream)
{
    const float* x  = (const float*)d_in[0];
    const float* Wg = (const float*)d_in[1];
    const float* We = (const float*)d_in[2];
    const float* be = (const float*)d_in[3];
    const float* W1 = (const float*)d_in[4];
    const float* b1 = (const float*)d_in[5];
    const float* W2 = (const float*)d_in[6];
    const float* b2 = (const float*)d_in[7];
    const float* Wo = (const float*)d_in[8];
    const float* bo = (const float*)d_in[9];
    float* out = (float*)d_out;

    const int M = 32768;    // B*T

    // workspace: 8 MB weights + 96 MB slotA + 64 MB slotB = 168 MB
    char* w = (char*)d_ws;
    unsigned short* Wep   = (unsigned short*)w; w += (size_t)1024*1536*2;  //  3 MB
    unsigned short* W1b   = (unsigned short*)w; w += (size_t)1024*1024*2;  //  2 MB
    unsigned short* W2b   = (unsigned short*)w; w += (size_t)1024*1024*2;  //  2 MB
    unsigned short* Wob   = (unsigned short*)w; w += (size_t)512*1024*2;   //  1 MB
    unsigned short* slotA = (unsigned short*)w; w += (size_t)M*1536*2;     // 96 MB
    unsigned short* slotB = (unsigned short*)w; w += (size_t)M*1024*2;     // 64 MB
    unsigned short* u  = slotA;   // [M,1536]
    unsigned short* o1 = slotA;   // [M,1024] (u dead after GEMM-1)
    unsigned short* he = slotB;   // [M,1024]
    unsigned short* o2 = slotB;   // [M,1024] (he dead after GEMM-2)

    hipLaunchKernelGGL(prep, dim3(10240), dim3(256), 0, stream,
                       x, Wg, W1, W2, Wo, We, u, W1b, W2b, Wob, Wep);

    hipLaunchKernelGGL((gemm256<1,3,false>), dim3((M/256)*(1024/256)), dim3(512), 0, stream,
                       u,  Wep, be, he,  M, 1024, 1536);
    hipLaunchKernelGGL((gemm256<2,1,false>), dim3((M/256)*(1024/256)), dim3(512), 0, stream,
                       he, W1b, b1, o1,  M, 1024, 1024);
    hipLaunchKernelGGL((gemm256<2,1,false>), dim3((M/256)*(1024/256)), dim3(512), 0, stream,
                       o1, W2b, b2, o2,  M, 1024, 1024);
    hipLaunchKernelGGL((gemm256<0,1,true>),  dim3((M/256)*(512/256)),  dim3(512), 0, stream,
                       o2, Wob, bo, out, M, 512, 1024);
}